// Round 5
// baseline (247.032 us; speedup 1.0000x reference)
//
#include <hip/hip_runtime.h>
#include <math.h>

#define NPAR 8
#define DIM  16
#define HID  128
#define BATCH 4096
#define VSTRF 132              // stride (floats) per 128-vector in LDS
#define NVEC 9                 // base + 8 tangent directions

typedef float v4f __attribute__((ext_vector_type(4)));

// Packed f32 weights (exact copies of f32 inputs) in static device memory.
// Layout (float offsets): PF2@0 PB2@16384 PF3@32768 PB3@49152 PF4@65536 PB4@81920 PB1@98304
__device__ float g_wsf[6*HID*HID + HID*DIM];

__device__ __forceinline__ float sigf(float z){ return 1.0f/(1.0f+__expf(-z)); }
__device__ __forceinline__ float spf(float z){ return fmaxf(z,0.0f)+log1pf(__expf(-fabsf(z))); }

// Destination-indexed (coalesced-write) packer. Each thread writes one float4.
__global__ __launch_bounds__(256)
void pack_weights(const float* __restrict__ W1, const float* __restrict__ W2,
                  const float* __restrict__ W3, const float* __restrict__ W4) {
  int t = blockIdx.x*blockDim.x + threadIdx.x;   // 25088 threads total
  int p4 = t*4;
  float4 r;
  if (p4 < 6*HID*HID) {
    int ri = p4 >> 14;                            // 0..5: PF2 PB2 PF3 PB3 PF4 PB4
    const float* W = (ri < 2) ? W2 : ((ri < 4) ? W3 : W4);
    int p  = p4 & 16383;
    int low = p & 127;
    int B  = p >> 7;
    int jo = (B & 3)*32 + (low >> 2);
    int T  = B >> 2;
    int kr0 = (T >> 4)*64 + (T & 15)*4;
    if ((ri & 1) == 0) {
      r = *((const float4*)(W + jo*HID + kr0));   // contiguous row-major read
    } else {
      r.x = W[(kr0+0)*HID + jo];
      r.y = W[(kr0+1)*HID + jo];
      r.z = W[(kr0+2)*HID + jo];
      r.w = W[(kr0+3)*HID + jo];
    }
  } else {
    int rr = p4 - 6*HID*HID;                      // 0..2047
    int k0 = (rr >> 6)*4;
    int m2 = (rr >> 2) & 15;
    r.x = W1[(k0+0)*DIM + m2];
    r.y = W1[(k0+1)*DIM + m2];
    r.z = W1[(k0+2)*DIM + m2];
    r.w = W1[(k0+3)*DIM + m2];
  }
  *((float4*)(g_wsf + p4)) = r;
}

// 2-wave split-K fused 9-vector GEMV, SCALAR v_fma_f32 core (v_pk_fma_f32 is
// quarter-rate on gfx950 — scalar FMA has 2x the FLOP throughput).
// Even/odd-k accumulator chains exactly reproduce the packed version's
// per-row summation order (bitwise-identical results).
// Wave w owns output rows [w*64, w*64+64). Lane (o,kh) accumulates k-half kh
// for rows {w*64+o, w*64+o+32}; after the shfl_xor(32) combine the lane keeps
// its single row j = w*64 + 32*kh + o.
__device__ __forceinline__ void gemv9s(const float* __restrict__ Wbase,
    const float* __restrict__ bin, int o, int kh, int w, float* z) {
  const v4f* Wq = (const v4f*)Wbase;
  const float* hb = bin + kh*64;
  float e0[NVEC], o0[NVEC], e1[NVEC], o1[NVEC];
#pragma unroll
  for (int v=0;v<NVEC;++v){ e0[v]=0.0f; o0[v]=0.0f; e1[v]=0.0f; o1[v]=0.0f; }
#pragma unroll 2
  for (int q=0;q<16;++q){
    int base = ((kh*16+q)*4)*32 + w*64 + o;
    v4f w0 = Wq[base], w1 = Wq[base+32];
#pragma unroll
    for (int v=0;v<NVEC;++v){
      v4f h = *((const v4f*)(hb + v*VSTRF + 4*q));   // LDS broadcast (2 addrs/wave)
      e0[v] = fmaf(w0.x, h.x, e0[v]); e0[v] = fmaf(w0.z, h.z, e0[v]);
      o0[v] = fmaf(w0.y, h.y, o0[v]); o0[v] = fmaf(w0.w, h.w, o0[v]);
      e1[v] = fmaf(w1.x, h.x, e1[v]); e1[v] = fmaf(w1.z, h.z, e1[v]);
      o1[v] = fmaf(w1.y, h.y, o1[v]); o1[v] = fmaf(w1.w, h.w, o1[v]);
    }
  }
#pragma unroll
  for (int v=0;v<NVEC;++v){
    float u0 = e0[v] + o0[v];
    float u1 = e1[v] + o1[v];
    u0 += __shfl_xor(u0,32);
    u1 += __shfl_xor(u1,32);
    z[v] = kh ? u1 : u0;
  }
}

__global__ __launch_bounds__(128)
void lnn_main(const float* __restrict__ x, const float* __restrict__ W1,
              const float* __restrict__ b1, const float* __restrict__ b2,
              const float* __restrict__ b3, const float* __restrict__ b4,
              const float* __restrict__ W5, float* __restrict__ out) {
  const int t  = threadIdx.x;        // 0..127
  const int l  = t & 63;             // lane in wave
  const int o  = l & 31;
  const int kh = l >> 5;
  const int w  = t >> 6;             // wave index = output-row half
  const int j  = w*64 + 32*kh + o;   // this lane's single output row
  const int s  = blockIdx.x;         // one sample per block

  __shared__ __align__(16) float buf[NVEC*VSTRF];  // base @0, tangents @(1+i)
  __shared__ float xs[16];
  __shared__ float hH[8*16];          // H[8+dd][m]
  __shared__ float hJs[16];           // J[m]

  if (t < DIM) xs[t] = x[s*DIM + t];
  __syncthreads();

  // ---- Phase 1: layer 1, one row per lane ----
  const float4* W1v = (const float4*)W1;
  float s1;
  float w1f[8];
  {
    float4 a0 = W1v[j*4+0], a1 = W1v[j*4+1], a2 = W1v[j*4+2], a3 = W1v[j*4+3];
    float z1 = b1[j];
    z1 = fmaf(a0.x, xs[0],  z1); z1 = fmaf(a0.y, xs[1],  z1);
    z1 = fmaf(a0.z, xs[2],  z1); z1 = fmaf(a0.w, xs[3],  z1);
    z1 = fmaf(a1.x, xs[4],  z1); z1 = fmaf(a1.y, xs[5],  z1);
    z1 = fmaf(a1.z, xs[6],  z1); z1 = fmaf(a1.w, xs[7],  z1);
    z1 = fmaf(a2.x, xs[8],  z1); z1 = fmaf(a2.y, xs[9],  z1);
    z1 = fmaf(a2.z, xs[10], z1); z1 = fmaf(a2.w, xs[11], z1);
    z1 = fmaf(a3.x, xs[12], z1); z1 = fmaf(a3.y, xs[13], z1);
    z1 = fmaf(a3.z, xs[14], z1); z1 = fmaf(a3.w, xs[15], z1);
    s1 = sigf(z1);
    buf[j] = spf(z1);
    w1f[0]=a2.x; w1f[1]=a2.y; w1f[2]=a2.z; w1f[3]=a2.w;
    w1f[4]=a3.x; w1f[5]=a3.y; w1f[6]=a3.z; w1f[7]=a3.w;
#pragma unroll
    for (int i=0;i<8;++i) buf[(1+i)*VSTRF + j] = s1*w1f[i];   // t_h1
  }
  __syncthreads();

  float z[NVEC];

  // ---- Phase 2: layer 2 forward (PF2) ----
  gemv9s(g_wsf + 0, buf, o, kh, w, z);
  float z2 = z[0] + b2[j];
  float t2[8];
#pragma unroll
  for (int i=0;i<8;++i) t2[i] = z[1+i];
  float s2 = sigf(z2);
  __syncthreads();
  buf[j] = spf(z2);
#pragma unroll
  for (int i=0;i<8;++i) buf[(1+i)*VSTRF + j] = s2*z[1+i];
  __syncthreads();

  // ---- Phase 3: layer 3 forward (PF3) ----
  gemv9s(g_wsf + 32768, buf, o, kh, w, z);
  float z3 = z[0] + b3[j];
  float t3[8];
#pragma unroll
  for (int i=0;i<8;++i) t3[i] = z[1+i];
  float s3 = sigf(z3);
  __syncthreads();
  buf[j] = spf(z3);
#pragma unroll
  for (int i=0;i<8;++i) buf[(1+i)*VSTRF + j] = s3*z[1+i];
  __syncthreads();

  // ---- Phase 4+5: layer 4 forward (PF4) + head ----
  gemv9s(g_wsf + 65536, buf, o, kh, w, z);
  {
    float z4 = z[0] + b4[j];
    float w5 = W5[j];
    float sa = sigf(z4);
    float ca = w5*sa*(1.0f-sa);
    __syncthreads();
    buf[j] = w5*sa;                                   // g_z4
#pragma unroll
    for (int i=0;i<8;++i) buf[(1+i)*VSTRF + j] = ca*z[1+i];  // u_z4
  }
  __syncthreads();

  // ---- Phase 6: backward through W4^T (PB4) ----
  gemv9s(g_wsf + 81920, buf, o, kh, w, z);
  {
    float da = s3*(1.0f-s3)*z[0];
    __syncthreads();
    buf[j] = z[0]*s3;                                 // g_z3
#pragma unroll
    for (int i=0;i<8;++i) buf[(1+i)*VSTRF + j] = fmaf(z[1+i], s3, da*t3[i]);  // u_z3
  }
  __syncthreads();

  // ---- Phase 7: backward through W3^T (PB3) ----
  gemv9s(g_wsf + 49152, buf, o, kh, w, z);
  {
    float da = s2*(1.0f-s2)*z[0];
    __syncthreads();
    buf[j] = z[0]*s2;                                 // g_z2
#pragma unroll
    for (int i=0;i<8;++i) buf[(1+i)*VSTRF + j] = fmaf(z[1+i], s2, da*t2[i]);  // u_z2
  }
  __syncthreads();

  // ---- Phase 8: backward through W2^T (PB2); W1 tangent cols from phase-1 regs ----
  gemv9s(g_wsf + 16384, buf, o, kh, w, z);
  {
    float da = s1*(1.0f-s1)*z[0];
    __syncthreads();
    buf[j] = z[0]*s1;                                 // g_z1
#pragma unroll
    for (int i=0;i<8;++i) buf[(1+i)*VSTRF + j] = fmaf(z[1+i], s1, da*w1f[i]); // u_z1
  }
  __syncthreads();

  // ---- Phase 9: H rows (8..15) + J via W1^T (PB1); 8 rows over 128 lanes ----
  {
    const int m = t & 15, dd = t >> 4;    // dd in 0..7
    const v4f* P1 = (const v4f*)(g_wsf + 98304);
    float aHe=0.0f, aHo=0.0f, aJe=0.0f, aJo=0.0f;
#pragma unroll 4
    for (int q=0; q<32; ++q){
      v4f wq = P1[q*DIM + m];             // W1[4q..4q+3][m]
      v4f u0 = *((const v4f*)(buf + (1+dd)*VSTRF + 4*q));
      v4f gg = *((const v4f*)(buf + 4*q));
      aHe = fmaf(wq.x, u0.x, aHe); aHe = fmaf(wq.z, u0.z, aHe);
      aHo = fmaf(wq.y, u0.y, aHo); aHo = fmaf(wq.w, u0.w, aHo);
      aJe = fmaf(wq.x, gg.x, aJe); aJe = fmaf(wq.z, gg.z, aJe);
      aJo = fmaf(wq.y, gg.y, aJo); aJo = fmaf(wq.w, gg.w, aJo);
    }
    hH[dd*16 + m] = aHe + aHo;            // H[8+dd][m]
    if (dd == 0) hJs[m] = aJe + aJo;      // J[m]
  }
  __syncthreads();

  // ---- Phase 10: y = pinv(B) @ (J[:8] - C qdot); wave 0 only ----
  if (t < 64) {
    const int r = t >> 3, c = t & 7;
    float Bv = hH[r*16 + 8 + c];           // B[r][c] = H[8+r][8+c]
    float Cr = hH[r*16 + c];               // C[r][c] = H[8+r][c]
    float Jr = hJs[r];                     // J[r]
    float p0 = Cr * xs[8 + c];
    p0 += __shfl_xor(p0, 1); p0 += __shfl_xor(p0, 2); p0 += __shfl_xor(p0, 4);
    float rhs = Jr - p0;

    // symmetrize
    float Bt = __shfl(Bv, c*8 + r);
    float Am = 0.5f*(Bv + Bt);
    float Vm = (r == c) ? 1.0f : 0.0f;

    // Parallel-order (round-robin) Jacobi: 4 disjoint pairs/step, 7 steps/sweep, 4 sweeps.
    for (int sweep = 0; sweep < 4; ++sweep) {
#pragma unroll
      for (int rr = 0; rr < 7; ++rr) {
        int pc = (c == 7) ? rr : ((c == rr) ? 7 : (2*rr + 7 - c) % 7);
        int cp = min(c, pc), cq = max(c, pc);
        float App = __shfl(Am, cp*8+cp);
        float Aqq = __shfl(Am, cq*8+cq);
        float Apq = __shfl(Am, cp*8+cq);
        float tau = (Aqq - App) / (2.0f*Apq);
        float tt  = (tau >= 0.0f ? 1.0f : -1.0f) / (fabsf(tau) + sqrtf(1.0f + tau*tau));
        float cth = 1.0f / sqrtf(1.0f + tt*tt);
        float sth = tt * cth;
        if (fabsf(Apq) < 1e-30f) { cth = 1.0f; sth = 0.0f; }   // guard 0/0 -> NaN
        float cthr = __shfl(cth, r*8+r);
        float sthr = __shfl(sth, r*8+r);
        // column rotation: M = A*G
        float Arp = __shfl(Am, r*8+cp);
        float Arq = __shfl(Am, r*8+cq);
        float colv = (c == cp) ? (cth*Arp - sth*Arq) : (sth*Arp + cth*Arq);
        // row rotation: A = G^T*M
        int pr2 = (r == 7) ? rr : ((r == rr) ? 7 : (2*rr + 7 - r) % 7);
        int rp = min(r, pr2), rq = max(r, pr2);
        float Mpc = __shfl(colv, rp*8+c);
        float Mqc = __shfl(colv, rq*8+c);
        Am = (r == rp) ? (cthr*Mpc - sthr*Mqc) : (sthr*Mpc + cthr*Mqc);
        // V = V*G
        float Vrp = __shfl(Vm, r*8+cp);
        float Vrq = __shfl(Vm, r*8+cq);
        Vm = (c == cp) ? (cth*Vrp - sth*Vrq) : (sth*Vrp + cth*Vrq);
      }
    }

    // eigenvalue for this lane's column, and sigma_max = max |diag|
    float lam_c = __shfl(Am, c*8 + c);
    float adiag = (r == c) ? fabsf(Am) : 0.0f;
#pragma unroll
    for (int off = 32; off; off >>= 1) adiag = fmaxf(adiag, __shfl_xor(adiag, off));
    float cutoff = 9.5367431640625e-06f * adiag;   // 10*max(M,N)*eps_f32 * sigma_max

    // p_c = sum_r V[r][c]*rhs_r
    float pr = Vm * rhs;
    pr += __shfl_xor(pr, 8); pr += __shfl_xor(pr, 16); pr += __shfl_xor(pr, 32);
    float ww = (fabsf(lam_c) > cutoff) ? (pr / lam_c) : 0.0f;
    // y_r = sum_c V[r][c]*w_c
    float yr = Vm * ww;
    yr += __shfl_xor(yr, 1); yr += __shfl_xor(yr, 2); yr += __shfl_xor(yr, 4);
    if (c == 0) out[s*NPAR + r] = yr;
  }
}

extern "C" void kernel_launch(void* const* d_in, const int* in_sizes, int n_in,
                              void* d_out, int out_size, void* d_ws, size_t ws_size,
                              hipStream_t stream) {
  (void)in_sizes; (void)n_in; (void)out_size; (void)d_ws; (void)ws_size;
  const float* x  = (const float*)d_in[0];
  const float* W1 = (const float*)d_in[1];
  const float* b1 = (const float*)d_in[2];
  const float* W2 = (const float*)d_in[3];
  const float* b2 = (const float*)d_in[4];
  const float* W3 = (const float*)d_in[5];
  const float* b3 = (const float*)d_in[6];
  const float* W4 = (const float*)d_in[7];
  const float* b4 = (const float*)d_in[8];
  const float* W5 = (const float*)d_in[9];
  float* out = (float*)d_out;

  pack_weights<<<98, 256, 0, stream>>>(W1, W2, W3, W4);
  lnn_main<<<BATCH, 128, 0, stream>>>(x, W1, b1, b2, b3, b4, W5, out);
}

// Round 6
// 224.264 us; speedup vs baseline: 1.1015x; 1.1015x over previous
//
#include <hip/hip_runtime.h>
#include <math.h>

#define NPAR 8
#define DIM  16
#define HID  128
#define BATCH 4096
#define VSTRF 132              // stride (floats) per 128-vector in LDS
#define NVEC 9                 // base + 8 tangent directions

typedef float v2f __attribute__((ext_vector_type(2)));
typedef float v4f __attribute__((ext_vector_type(4)));

// d = a*b + d per 2-lane component (packed f32 FMA).
#define PKFMA(d, a, b) asm("v_pk_fma_f32 %0, %1, %2, %0" : "+v"(d) : "v"(a), "v"(b))

// Packed f32 weights (exact copies of f32 inputs) in static device memory.
// Layout (float offsets): PF2@0 PB2@16384 PF3@32768 PB3@49152 PF4@65536 PB4@81920 PB1@98304
__device__ float g_wsf[6*HID*HID + HID*DIM];

__device__ __forceinline__ float sigf(float z){ return 1.0f/(1.0f+__expf(-z)); }
__device__ __forceinline__ float spf(float z){ return fmaxf(z,0.0f)+log1pf(__expf(-fabsf(z))); }

// Destination-indexed (coalesced-write) packer. Each thread writes one float4.
__global__ __launch_bounds__(256)
void pack_weights(const float* __restrict__ W1, const float* __restrict__ W2,
                  const float* __restrict__ W3, const float* __restrict__ W4) {
  int t = blockIdx.x*blockDim.x + threadIdx.x;   // 25088 threads total
  int p4 = t*4;
  float4 r;
  if (p4 < 6*HID*HID) {
    int ri = p4 >> 14;                            // 0..5: PF2 PB2 PF3 PB3 PF4 PB4
    const float* W = (ri < 2) ? W2 : ((ri < 4) ? W3 : W4);
    int p  = p4 & 16383;
    int low = p & 127;
    int B  = p >> 7;
    int jo = (B & 3)*32 + (low >> 2);
    int T  = B >> 2;
    int kr0 = (T >> 4)*64 + (T & 15)*4;
    if ((ri & 1) == 0) {
      r = *((const float4*)(W + jo*HID + kr0));   // contiguous row-major read
    } else {
      r.x = W[(kr0+0)*HID + jo];
      r.y = W[(kr0+1)*HID + jo];
      r.z = W[(kr0+2)*HID + jo];
      r.w = W[(kr0+3)*HID + jo];
    }
  } else {
    int rr = p4 - 6*HID*HID;                      // 0..2047
    int k0 = (rr >> 6)*4;
    int m2 = (rr >> 2) & 15;
    r.x = W1[(k0+0)*DIM + m2];
    r.y = W1[(k0+1)*DIM + m2];
    r.z = W1[(k0+2)*DIM + m2];
    r.w = W1[(k0+3)*DIM + m2];
  }
  *((float4*)(g_wsf + p4)) = r;
}

// 2-wave split-K fused 9-vector GEMV with software-pipelined double-buffered
// prefetch: while the FMA block for step q executes, the h-vectors (LDS) and
// weight rows (L2) for step q+1 are already in flight into the alternate
// register buffer. Arithmetic order per accumulator is identical to the
// non-pipelined version (bitwise-identical results).
// Wave w owns output rows [w*64, w*64+64). Lane (o,kh) accumulates k-half kh
// for rows {w*64+o, w*64+o+32}; after the shfl_xor(32) combine the lane keeps
// its single row j = w*64 + 32*kh + o.
// NOTE: the tail prefetch (q+2==16) reads the LDS pad column (VSTRF=132>128)
// and the next weight region of g_wsf — both in-bounds, values unused.
__device__ __forceinline__ void gemv9p(const float* __restrict__ Wbase,
    const float* __restrict__ bin, int o, int kh, int w, float* z) {
  const v4f* Wq = (const v4f*)Wbase;
  const float* hb = bin + kh*64;
  v2f acc0[NVEC], acc1[NVEC];
#pragma unroll
  for (int v=0;v<NVEC;++v){ acc0[v]=(v2f){0.0f,0.0f}; acc1[v]=(v2f){0.0f,0.0f}; }

  int base = (kh*16*4)*32 + w*64 + o;      // v4f-unit index for q=0
  v4f wA0 = Wq[base], wA1 = Wq[base+32];
  v4f wB0, wB1;
  v4f hA[NVEC], hB[NVEC];
#pragma unroll
  for (int v=0;v<NVEC;++v) hA[v] = *((const v4f*)(hb + v*VSTRF));

#pragma unroll 1
  for (int q=0; q<16; q+=2){
    // prefetch q+1 into B buffers
    wB0 = Wq[base+128]; wB1 = Wq[base+160];
#pragma unroll
    for (int v=0;v<NVEC;++v) hB[v] = *((const v4f*)(hb + v*VSTRF + 4*q + 4));
    // compute q from A buffers
    {
      v2f w0a=wA0.xy, w0b=wA0.zw, w1a=wA1.xy, w1b=wA1.zw;
#pragma unroll
      for (int v=0;v<NVEC;++v){
        v2f ha=hA[v].xy, hc=hA[v].zw;
        PKFMA(acc0[v], w0a, ha); PKFMA(acc0[v], w0b, hc);
        PKFMA(acc1[v], w1a, ha); PKFMA(acc1[v], w1b, hc);
      }
    }
    // prefetch q+2 into A buffers (tail over-read is in-bounds, unused)
    wA0 = Wq[base+256]; wA1 = Wq[base+288];
#pragma unroll
    for (int v=0;v<NVEC;++v) hA[v] = *((const v4f*)(hb + v*VSTRF + 4*q + 8));
    // compute q+1 from B buffers
    {
      v2f w0a=wB0.xy, w0b=wB0.zw, w1a=wB1.xy, w1b=wB1.zw;
#pragma unroll
      for (int v=0;v<NVEC;++v){
        v2f ha=hB[v].xy, hc=hB[v].zw;
        PKFMA(acc0[v], w0a, ha); PKFMA(acc0[v], w0b, hc);
        PKFMA(acc1[v], w1a, ha); PKFMA(acc1[v], w1b, hc);
      }
    }
    base += 256;
  }

#pragma unroll
  for (int v=0;v<NVEC;++v){
    float u0 = acc0[v].x + acc0[v].y;
    float u1 = acc1[v].x + acc1[v].y;
    u0 += __shfl_xor(u0,32);
    u1 += __shfl_xor(u1,32);
    z[v] = kh ? u1 : u0;
  }
}

__global__ __launch_bounds__(128)
void lnn_main(const float* __restrict__ x, const float* __restrict__ W1,
              const float* __restrict__ b1, const float* __restrict__ b2,
              const float* __restrict__ b3, const float* __restrict__ b4,
              const float* __restrict__ W5, float* __restrict__ out) {
  const int t  = threadIdx.x;        // 0..127
  const int l  = t & 63;             // lane in wave
  const int o  = l & 31;
  const int kh = l >> 5;
  const int w  = t >> 6;             // wave index = output-row half
  const int j  = w*64 + 32*kh + o;   // this lane's single output row
  const int s  = blockIdx.x;         // one sample per block

  __shared__ __align__(16) float buf[NVEC*VSTRF];  // base @0, tangents @(1+i)
  __shared__ float xs[16];
  __shared__ float hH[8*16];          // H[8+dd][m]
  __shared__ float hJs[16];           // J[m]

  if (t < DIM) xs[t] = x[s*DIM + t];
  __syncthreads();

  // ---- Phase 1: layer 1, one row per lane ----
  const float4* W1v = (const float4*)W1;
  float s1;
  float w1f[8];
  {
    float4 a0 = W1v[j*4+0], a1 = W1v[j*4+1], a2 = W1v[j*4+2], a3 = W1v[j*4+3];
    float z1 = b1[j];
    z1 = fmaf(a0.x, xs[0],  z1); z1 = fmaf(a0.y, xs[1],  z1);
    z1 = fmaf(a0.z, xs[2],  z1); z1 = fmaf(a0.w, xs[3],  z1);
    z1 = fmaf(a1.x, xs[4],  z1); z1 = fmaf(a1.y, xs[5],  z1);
    z1 = fmaf(a1.z, xs[6],  z1); z1 = fmaf(a1.w, xs[7],  z1);
    z1 = fmaf(a2.x, xs[8],  z1); z1 = fmaf(a2.y, xs[9],  z1);
    z1 = fmaf(a2.z, xs[10], z1); z1 = fmaf(a2.w, xs[11], z1);
    z1 = fmaf(a3.x, xs[12], z1); z1 = fmaf(a3.y, xs[13], z1);
    z1 = fmaf(a3.z, xs[14], z1); z1 = fmaf(a3.w, xs[15], z1);
    s1 = sigf(z1);
    buf[j] = spf(z1);
    w1f[0]=a2.x; w1f[1]=a2.y; w1f[2]=a2.z; w1f[3]=a2.w;
    w1f[4]=a3.x; w1f[5]=a3.y; w1f[6]=a3.z; w1f[7]=a3.w;
#pragma unroll
    for (int i=0;i<8;++i) buf[(1+i)*VSTRF + j] = s1*w1f[i];   // t_h1
  }
  __syncthreads();

  float z[NVEC];

  // ---- Phase 2: layer 2 forward (PF2) ----
  gemv9p(g_wsf + 0, buf, o, kh, w, z);
  float z2 = z[0] + b2[j];
  float t2[8];
#pragma unroll
  for (int i=0;i<8;++i) t2[i] = z[1+i];
  float s2 = sigf(z2);
  __syncthreads();
  buf[j] = spf(z2);
#pragma unroll
  for (int i=0;i<8;++i) buf[(1+i)*VSTRF + j] = s2*z[1+i];
  __syncthreads();

  // ---- Phase 3: layer 3 forward (PF3) ----
  gemv9p(g_wsf + 32768, buf, o, kh, w, z);
  float z3 = z[0] + b3[j];
  float t3[8];
#pragma unroll
  for (int i=0;i<8;++i) t3[i] = z[1+i];
  float s3 = sigf(z3);
  __syncthreads();
  buf[j] = spf(z3);
#pragma unroll
  for (int i=0;i<8;++i) buf[(1+i)*VSTRF + j] = s3*z[1+i];
  __syncthreads();

  // ---- Phase 4+5: layer 4 forward (PF4) + head ----
  gemv9p(g_wsf + 65536, buf, o, kh, w, z);
  {
    float z4 = z[0] + b4[j];
    float w5 = W5[j];
    float sa = sigf(z4);
    float ca = w5*sa*(1.0f-sa);
    __syncthreads();
    buf[j] = w5*sa;                                   // g_z4
#pragma unroll
    for (int i=0;i<8;++i) buf[(1+i)*VSTRF + j] = ca*z[1+i];  // u_z4
  }
  __syncthreads();

  // ---- Phase 6: backward through W4^T (PB4) ----
  gemv9p(g_wsf + 81920, buf, o, kh, w, z);
  {
    float da = s3*(1.0f-s3)*z[0];
    __syncthreads();
    buf[j] = z[0]*s3;                                 // g_z3
#pragma unroll
    for (int i=0;i<8;++i) buf[(1+i)*VSTRF + j] = fmaf(z[1+i], s3, da*t3[i]);  // u_z3
  }
  __syncthreads();

  // ---- Phase 7: backward through W3^T (PB3) ----
  gemv9p(g_wsf + 49152, buf, o, kh, w, z);
  {
    float da = s2*(1.0f-s2)*z[0];
    __syncthreads();
    buf[j] = z[0]*s2;                                 // g_z2
#pragma unroll
    for (int i=0;i<8;++i) buf[(1+i)*VSTRF + j] = fmaf(z[1+i], s2, da*t2[i]);  // u_z2
  }
  __syncthreads();

  // ---- Phase 8: backward through W2^T (PB2); W1 tangent cols from phase-1 regs ----
  gemv9p(g_wsf + 16384, buf, o, kh, w, z);
  {
    float da = s1*(1.0f-s1)*z[0];
    __syncthreads();
    buf[j] = z[0]*s1;                                 // g_z1
#pragma unroll
    for (int i=0;i<8;++i) buf[(1+i)*VSTRF + j] = fmaf(z[1+i], s1, da*w1f[i]); // u_z1
  }
  __syncthreads();

  // ---- Phase 9: H rows (8..15) + J via W1^T (PB1); 8 rows over 128 lanes ----
  {
    const int m = t & 15, dd = t >> 4;    // dd in 0..7
    const v4f* P1 = (const v4f*)(g_wsf + 98304);
    v2f aH={0.0f,0.0f}, aJ={0.0f,0.0f};
#pragma unroll 4
    for (int q=0; q<32; ++q){
      v4f wq = P1[q*DIM + m];             // W1[4q..4q+3][m]
      v2f wa=wq.xy, wb=wq.zw;
      v4f u0 = *((const v4f*)(buf + (1+dd)*VSTRF + 4*q));
      v4f gg = *((const v4f*)(buf + 4*q));
      v2f ua=u0.xy, uc=u0.zw, ga=gg.xy, gc=gg.zw;
      PKFMA(aH, wa, ua); PKFMA(aH, wb, uc);
      PKFMA(aJ, wa, ga); PKFMA(aJ, wb, gc);
    }
    hH[dd*16 + m] = aH.x + aH.y;          // H[8+dd][m]
    if (dd == 0) hJs[m] = aJ.x + aJ.y;    // J[m]
  }
  __syncthreads();

  // ---- Phase 10: y = pinv(B) @ (J[:8] - C qdot); wave 0 only ----
  if (t < 64) {
    const int r = t >> 3, c = t & 7;
    float Bv = hH[r*16 + 8 + c];           // B[r][c] = H[8+r][8+c]
    float Cr = hH[r*16 + c];               // C[r][c] = H[8+r][c]
    float Jr = hJs[r];                     // J[r]
    float p0 = Cr * xs[8 + c];
    p0 += __shfl_xor(p0, 1); p0 += __shfl_xor(p0, 2); p0 += __shfl_xor(p0, 4);
    float rhs = Jr - p0;

    // symmetrize
    float Bt = __shfl(Bv, c*8 + r);
    float Am = 0.5f*(Bv + Bt);
    float Vm = (r == c) ? 1.0f : 0.0f;

    // Parallel-order (round-robin) Jacobi: 4 disjoint pairs/step, 7 steps/sweep, 4 sweeps.
    for (int sweep = 0; sweep < 4; ++sweep) {
#pragma unroll
      for (int rr = 0; rr < 7; ++rr) {
        int pc = (c == 7) ? rr : ((c == rr) ? 7 : (2*rr + 7 - c) % 7);
        int cp = min(c, pc), cq = max(c, pc);
        float App = __shfl(Am, cp*8+cp);
        float Aqq = __shfl(Am, cq*8+cq);
        float Apq = __shfl(Am, cp*8+cq);
        float tau = (Aqq - App) / (2.0f*Apq);
        float tt  = (tau >= 0.0f ? 1.0f : -1.0f) / (fabsf(tau) + sqrtf(1.0f + tau*tau));
        float cth = 1.0f / sqrtf(1.0f + tt*tt);
        float sth = tt * cth;
        if (fabsf(Apq) < 1e-30f) { cth = 1.0f; sth = 0.0f; }   // guard 0/0 -> NaN
        float cthr = __shfl(cth, r*8+r);
        float sthr = __shfl(sth, r*8+r);
        // column rotation: M = A*G
        float Arp = __shfl(Am, r*8+cp);
        float Arq = __shfl(Am, r*8+cq);
        float colv = (c == cp) ? (cth*Arp - sth*Arq) : (sth*Arp + cth*Arq);
        // row rotation: A = G^T*M
        int pr2 = (r == 7) ? rr : ((r == rr) ? 7 : (2*rr + 7 - r) % 7);
        int rp = min(r, pr2), rq = max(r, pr2);
        float Mpc = __shfl(colv, rp*8+c);
        float Mqc = __shfl(colv, rq*8+c);
        Am = (r == rp) ? (cthr*Mpc - sthr*Mqc) : (sthr*Mpc + cthr*Mqc);
        // V = V*G
        float Vrp = __shfl(Vm, r*8+cp);
        float Vrq = __shfl(Vm, r*8+cq);
        Vm = (c == cp) ? (cth*Vrp - sth*Vrq) : (sth*Vrp + cth*Vrq);
      }
    }

    // eigenvalue for this lane's column, and sigma_max = max |diag|
    float lam_c = __shfl(Am, c*8 + c);
    float adiag = (r == c) ? fabsf(Am) : 0.0f;
#pragma unroll
    for (int off = 32; off; off >>= 1) adiag = fmaxf(adiag, __shfl_xor(adiag, off));
    float cutoff = 9.5367431640625e-06f * adiag;   // 10*max(M,N)*eps_f32 * sigma_max

    // p_c = sum_r V[r][c]*rhs_r
    float pr = Vm * rhs;
    pr += __shfl_xor(pr, 8); pr += __shfl_xor(pr, 16); pr += __shfl_xor(pr, 32);
    float ww = (fabsf(lam_c) > cutoff) ? (pr / lam_c) : 0.0f;
    // y_r = sum_c V[r][c]*w_c
    float yr = Vm * ww;
    yr += __shfl_xor(yr, 1); yr += __shfl_xor(yr, 2); yr += __shfl_xor(yr, 4);
    if (c == 0) out[s*NPAR + r] = yr;
  }
}

extern "C" void kernel_launch(void* const* d_in, const int* in_sizes, int n_in,
                              void* d_out, int out_size, void* d_ws, size_t ws_size,
                              hipStream_t stream) {
  (void)in_sizes; (void)n_in; (void)out_size; (void)d_ws; (void)ws_size;
  const float* x  = (const float*)d_in[0];
  const float* W1 = (const float*)d_in[1];
  const float* b1 = (const float*)d_in[2];
  const float* W2 = (const float*)d_in[3];
  const float* b2 = (const float*)d_in[4];
  const float* W3 = (const float*)d_in[5];
  const float* b3 = (const float*)d_in[6];
  const float* W4 = (const float*)d_in[7];
  const float* b4 = (const float*)d_in[8];
  const float* W5 = (const float*)d_in[9];
  float* out = (float*)d_out;

  pack_weights<<<98, 256, 0, stream>>>(W1, W2, W3, W4);
  lnn_main<<<BATCH, 128, 0, stream>>>(x, W1, b1, b2, b3, b4, W5, out);
}